// Round 4
// baseline (70.971 us; speedup 1.0000x reference)
//
#include <hip/hip_runtime.h>
#include <hip/hip_cooperative_groups.h>
#include <math.h>

namespace cg = cooperative_groups;

#define BATCH 2
#define LLEN  2080
#define MCH   2
#define TT    51
#define FF    80
#define HOP   40
#define KW    1600
#define OUTL  2040
#define NT    640
#define NB    (BATCH * TT * MCH)   // 204
#define PI_F  3.14159265358979323846f

struct SharedBlk {
    float2 xs[2 * FF];       // samples: frame t [0:80), frame t-1 [80:160)
    float2 tw[FF];           // e^{+i 2pi r/80}
    float2 Yt2[2 * FF];      // double-stored Yt: Yt2[j] = Yt[(j-20)%80]
    float2 Yp[FF];
    float2 Wsh[KW];          // w, [n1][n2]
    float2 Zall[40][2 * FF]; // double-stored Z rows (overlaid by reductions)
    float2 dvec[FF];
};   // ~67 KB

// ---------------- pipeline: STFT + delta + iDFT for one (b,t,m) ----------------
__device__ __forceinline__ void pipeline(
    SharedBlk& S,
    const float* __restrict__ xr, const float* __restrict__ xi,
    const float* __restrict__ wr, const float* __restrict__ wi,
    const float* __restrict__ br, const float* __restrict__ bi,
    float2* __restrict__ Fr)
{
    float2* flat = &S.Zall[0][0];   // 6400-entry overlay region

    int tid = threadIdx.x;
    int bid = blockIdx.x;
    int b   = bid / (TT * MCH);
    int rem = bid % (TT * MCH);
    int t   = rem / MCH;
    int mi  = rem % MCH;
    int tp  = (t + TT - 1) % TT;

    // ---- Phase 0: load samples + twiddles + w ----
    if (tid < FF) {
        int g = (b * LLEN + t * HOP + tid) * MCH + mi;
        S.xs[tid] = make_float2(xr[g], xi[g]);
        float s, c;
        sincosf((2.0f * PI_F / FF) * (float)tid, &s, &c);
        S.tw[tid] = make_float2(c, s);
    } else if (tid < 2 * FF) {
        int j = tid - FF;
        int g = (b * LLEN + tp * HOP + j) * MCH + mi;
        S.xs[tid] = make_float2(xr[g], xi[g]);
    } else {
        for (int k = tid - 2 * FF; k < KW; k += NT - 2 * FF)
            S.Wsh[k] = make_float2(wr[k], wi[k]);
    }
    __syncthreads();

    // ---- Phase 1: STFT both frames; 160 outputs x 4 partials x 20 MACs ----
    {
        int o    = tid >> 2;
        int part = tid & 3;
        int ff   = o % FF;
        int frm  = o / FF;
        const float2* xb = &S.xs[frm * FF];
        float2 a = make_float2(0.f, 0.f);
        int j0 = part * 20;
        int r  = (ff * j0) % FF;
        for (int j = j0; j < j0 + 20; ++j) {
            float2 xv = xb[j];
            float2 tv = S.tw[r];           // conj applied: e^{-i..}
            a.x += xv.x * tv.x + xv.y * tv.y;
            a.y += xv.y * tv.x - xv.x * tv.y;
            r += ff; if (r >= FF) r -= FF;
        }
        flat[part * 160 + o] = a;
    }
    __syncthreads();
    if (tid < 2 * FF) {
        float2 s = make_float2(0.f, 0.f);
        for (int p = 0; p < 4; ++p) {
            float2 v = flat[p * 160 + tid];
            s.x += v.x; s.y += v.y;
        }
        if (tid < FF) {
            S.Yt2[tid + 20] = s;
            S.Yt2[(tid < 60) ? (tid + 100) : (tid - 60)] = s;
        } else {
            S.Yp[tid - FF] = s;
        }
    }
    __syncthreads();

    // ---- Phase 2: build all 40 Z rows (3200 values, 5/thread), double-stored ----
    for (int i = 0; i < 5; ++i) {
        int zi = tid + i * NT;
        int jn = zi / FF;
        int g  = zi % FF;
        int n2 = jn - 20;
        int gm = g - n2; if (gm >= FF) gm -= FF; if (gm < 0) gm += FF;
        float2 a  = S.Yt2[g + 20], bm = S.Yt2[gm + 20];
        float2 cc = S.Yp[g],       dm = S.Yp[gm];
        float zre = a.x * bm.x + a.y * bm.y + cc.x * dm.x + cc.y * dm.y;
        float zim = a.y * bm.x - a.x * bm.y + cc.y * dm.x - cc.x * dm.y;
        float2 z = make_float2(zre, zim);
        S.Zall[jn][g + 20] = z;
        S.Zall[jn][(g < 60) ? (g + 100) : (g - 60)] = z;
    }
    __syncthreads();

    // ---- Phase 3: register sliding-window MAC over n1 ----
    float2 o0, o1, o2, o3, o4;
    int jn, fb;
    {
        jn = tid >> 4;          // n2 index 0..39
        int fg = tid & 15;
        fb = fg * 5;            // base frequency
        const float2* zz = S.Zall[jn];

        float2 S0 = make_float2(0.f,0.f), S1 = S0, S2 = S0, S3 = S0, S4 = S0;
        float2 w0 = zz[fb + 40], w1 = zz[fb + 41], w2 = zz[fb + 42],
               w3 = zz[fb + 43], w4 = zz[fb + 44];
        #pragma unroll
        for (int jn1 = 0; jn1 < 40; ++jn1) {
            float2 wv = S.Wsh[jn1 * 40 + jn];
            S0.x += wv.x * w0.x - wv.y * w0.y;  S0.y += wv.x * w0.y + wv.y * w0.x;
            S1.x += wv.x * w1.x - wv.y * w1.y;  S1.y += wv.x * w1.y + wv.y * w1.x;
            S2.x += wv.x * w2.x - wv.y * w2.y;  S2.y += wv.x * w2.y + wv.y * w2.x;
            S3.x += wv.x * w3.x - wv.y * w3.y;  S3.y += wv.x * w3.y + wv.y * w3.x;
            S4.x += wv.x * w4.x - wv.y * w4.y;  S4.y += wv.x * w4.y + wv.y * w4.x;
            if (jn1 < 39) {
                float2 nv = zz[fb + 39 - jn1];
                w4 = w3; w3 = w2; w2 = w1; w1 = w0; w0 = nv;
            }
        }
        float2 y;
        y = S.Yt2[fb + 0 - jn + 40]; o0 = make_float2(y.x*S0.x - y.y*S0.y, y.x*S0.y + y.y*S0.x);
        y = S.Yt2[fb + 1 - jn + 40]; o1 = make_float2(y.x*S1.x - y.y*S1.y, y.x*S1.y + y.y*S1.x);
        y = S.Yt2[fb + 2 - jn + 40]; o2 = make_float2(y.x*S2.x - y.y*S2.y, y.x*S2.y + y.y*S2.x);
        y = S.Yt2[fb + 3 - jn + 40]; o3 = make_float2(y.x*S3.x - y.y*S3.y, y.x*S3.y + y.y*S3.x);
        y = S.Yt2[fb + 4 - jn + 40]; o4 = make_float2(y.x*S4.x - y.y*S4.y, y.x*S4.y + y.y*S4.x);
    }
    __syncthreads();           // all Zall reads done before overlay writes
    flat[jn * FF + fb + 0] = o0;
    flat[jn * FF + fb + 1] = o1;
    flat[jn * FF + fb + 2] = o2;
    flat[jn * FF + fb + 3] = o3;
    flat[jn * FF + fb + 4] = o4;
    __syncthreads();

    // ---- tree-reduce 40 n2-partials: stage 1 (640 thr, 5 rows each) ----
    {
        int f = tid % FF;
        int p = tid / FF;      // 0..7
        float2 s = make_float2(0.f, 0.f);
        for (int q = 0; q < 5; ++q) {
            float2 v = flat[(p * 5 + q) * FF + f];
            s.x += v.x; s.y += v.y;
        }
        flat[3200 + p * FF + f] = s;
    }
    __syncthreads();
    if (tid < FF) {
        float2 s = make_float2(br[0], bi[0]);
        for (int p = 0; p < 8; ++p) {
            float2 v = flat[3200 + p * FF + tid];
            s.x += v.x; s.y += v.y;
        }
        S.dvec[tid] = s;
    }
    __syncthreads();

    // ---- Phase 4: iDFT; 80 outputs x 8 partials x 10 MACs ----
    {
        int j    = tid >> 3;
        int part = tid & 7;
        float2 a = make_float2(0.f, 0.f);
        int f0 = part * 10;
        int r  = (j * f0) % FF;
        for (int ff2 = f0; ff2 < f0 + 10; ++ff2) {
            float2 dv = S.dvec[ff2];
            float2 tv = S.tw[r];           // e^{+i 2pi j f/80}
            a.x += dv.x * tv.x - dv.y * tv.y;
            a.y += dv.x * tv.y + dv.y * tv.x;
            r += j; if (r >= FF) r -= FF;
        }
        flat[part * FF + j] = a;
    }
    __syncthreads();
    if (tid < FF) {
        float2 s = make_float2(0.f, 0.f);
        for (int p = 0; p < 8; ++p) {
            float2 v = flat[p * FF + tid];
            s.x += v.x; s.y += v.y;
        }
        s.x *= (1.0f / FF);
        s.y *= (1.0f / FF);
        Fr[((b * TT + t) * MCH + mi) * FF + tid] = s;
    }
}

// ---------------- per-element output: overlap-add, cov, residual, slice ----------------
__device__ __forceinline__ void out_elem(
    int idx,
    const float* __restrict__ xr, const float* __restrict__ xi,
    const float* __restrict__ ti, const float2* __restrict__ Fr,
    float* __restrict__ out, int out_size)
{
    int tot = BATCH * OUTL * MCH;
    if (idx >= tot) return;
    int mi  = idx % MCH;
    int rem = idx / MCH;
    int lo  = rem % OUTL;
    int b   = rem / OUTL;
    int l   = lo + 20;

    float P = exp2f(ti[b * 4] * 0.33219280948873623f) * 0.5f;  // 10^(x/10)/2

    int t1 = l / HOP;
    int t0 = t1 - 1;
    float2 acc = make_float2(0.f, 0.f);
    float cov = 0.f;
    if (t1 <= TT - 1) {
        float2 v = Fr[((b * TT + t1) * MCH + mi) * FF + (l - HOP * t1)];
        acc.x += v.x; acc.y += v.y; cov += 1.f;
    }
    if (t0 >= 0) {
        float2 v = Fr[((b * TT + t0) * MCH + mi) * FF + (l - HOP * t0)];
        acc.x += v.x; acc.y += v.y; cov += 1.f;
    }
    float inv = 1.0f / cov;
    acc.x *= inv; acc.y *= inv;

    int gi = (b * LLEN + l) * MCH + mi;
    float outr = xr[gi] + acc.x * P;
    if (out_size == tot) {
        out[idx] = outr;
    } else {
        float outi = xi[gi] + acc.y * P;
        out[idx * 2]     = outr;
        out[idx * 2 + 1] = outi;
    }
}

// ---------------- single cooperative kernel ----------------
__global__ __launch_bounds__(NT) void fused_coop(
    const float* __restrict__ xr, const float* __restrict__ xi,
    const float* __restrict__ ti,
    const float* __restrict__ wr, const float* __restrict__ wi,
    const float* __restrict__ br, const float* __restrict__ bi,
    float2* __restrict__ Fr, float* __restrict__ out, int out_size)
{
    __shared__ SharedBlk S;
    pipeline(S, xr, xi, wr, wi, br, bi, Fr);
    __threadfence();
    cg::this_grid().sync();
    out_elem(blockIdx.x * NT + threadIdx.x, xr, xi, ti, Fr, out, out_size);
}

// ---------------- fallback two-kernel path ----------------
__global__ __launch_bounds__(NT) void fused_kernel(
    const float* __restrict__ xr, const float* __restrict__ xi,
    const float* __restrict__ wr, const float* __restrict__ wi,
    const float* __restrict__ br, const float* __restrict__ bi,
    float2* __restrict__ Fr)
{
    __shared__ SharedBlk S;
    pipeline(S, xr, xi, wr, wi, br, bi, Fr);
}

__global__ void out_kernel(
    const float* __restrict__ xr, const float* __restrict__ xi,
    const float* __restrict__ ti, const float2* __restrict__ Fr,
    float* __restrict__ out, int out_size)
{
    out_elem(blockIdx.x * blockDim.x + threadIdx.x, xr, xi, ti, Fr, out, out_size);
}

extern "C" void kernel_launch(void* const* d_in, const int* in_sizes, int n_in,
                              void* d_out, int out_size, void* d_ws, size_t ws_size,
                              hipStream_t stream)
{
    const float* xr = (const float*)d_in[0];
    const float* xi = (const float*)d_in[1];
    const float* ti = (const float*)d_in[2];
    const float* wr = (const float*)d_in[3];
    const float* wi = (const float*)d_in[4];
    const float* br = (const float*)d_in[5];
    const float* bi = (const float*)d_in[6];

    float2* Fr = (float2*)d_ws;   // 204*80 float2 = 130.6 KB
    float*  out = (float*)d_out;

    void* args[10] = { (void*)&xr, (void*)&xi, (void*)&ti, (void*)&wr, (void*)&wi,
                       (void*)&br, (void*)&bi, (void*)&Fr, (void*)&out, (void*)&out_size };
    hipError_t err = hipLaunchCooperativeKernel((const void*)fused_coop,
                                                dim3(NB), dim3(NT), args, 0, stream);
    if (err != hipSuccess) {
        // deterministic fallback: identical math, two launches
        fused_kernel<<<NB, NT, 0, stream>>>(xr, xi, wr, wi, br, bi, Fr);
        int tot = BATCH * OUTL * MCH;
        out_kernel<<<(tot + 255) / 256, 256, 0, stream>>>(xr, xi, ti, Fr, out, out_size);
    }
}

// Round 5
// 21.396 us; speedup vs baseline: 3.3170x; 3.3170x over previous
//
#include <hip/hip_runtime.h>
#include <math.h>

#define BATCH 2
#define LLEN  2080
#define MCH   2
#define TT    51
#define FF    80
#define HOP   40
#define KW    1600
#define OUTL  2040
#define NT    640
#define NB    (BATCH * TT * MCH)   // 204
#define PI_F  3.14159265358979323846f

// ---------------- Kernel 1: STFT + delta spectrum (no iDFT) ----------------
// one block per (b,t,m): 204 blocks x 640 threads
__global__ __launch_bounds__(NT) void fused_k1(
    const float* __restrict__ xr, const float* __restrict__ xi,
    const float* __restrict__ wr, const float* __restrict__ wi,
    const float* __restrict__ br, const float* __restrict__ bi,
    float2* __restrict__ dvec_g)
{
    __shared__ float2 xs[2 * FF];       // frame t [0:80), frame t-1 [80:160)
    __shared__ float2 Yt2[2 * FF];      // double-stored Yt: Yt2[j] = Yt[(j-20)%80]
    __shared__ float2 Yp[FF];
    __shared__ float2 Wsh[KW];          // w, [n1][n2]
    __shared__ float2 Zall[40][2 * FF]; // double-stored Z rows (overlaid after phase 3)
    float2* flat = &Zall[0][0];         // 6400-float2 overlay

    int tid = threadIdx.x;
    int bid = blockIdx.x;
    int b   = bid / (TT * MCH);
    int rem = bid % (TT * MCH);
    int t   = rem / MCH;
    int mi  = rem % MCH;
    int tp  = (t + TT - 1) % TT;

    // ---- Phase 0: load samples (160 thr) + w (480 thr) ----
    if (tid < 2 * FF) {
        int frm = tid / FF, j = tid % FF;
        int tt  = frm == 0 ? t : tp;
        int g = (b * LLEN + tt * HOP + j) * MCH + mi;
        xs[tid] = make_float2(xr[g], xi[g]);
    } else {
        for (int k = tid - 2 * FF; k < KW; k += NT - 2 * FF)
            Wsh[k] = make_float2(wr[k], wi[k]);
    }
    __syncthreads();

    // ---- Phase 1: STFT both frames; 160 outputs x 4 lane-adjacent partials ----
    {
        int o    = tid >> 2;       // 0..159
        int part = tid & 3;
        int ff   = o % FF;
        int frm  = o / FF;
        const float2* xb = &xs[frm * FF];

        // tv = e^{-i 2pi ff j/80}, j0 = part*20 -> angle = -(pi/2)*ff*part (exact quadrant)
        int q = (ff * part) & 3;
        float2 tv = (q == 0) ? make_float2(1.f, 0.f)
                  : (q == 1) ? make_float2(0.f, -1.f)
                  : (q == 2) ? make_float2(-1.f, 0.f)
                  :            make_float2(0.f, 1.f);
        float sp, cp;
        sincosf(-(2.0f * PI_F / FF) * (float)ff, &sp, &cp);
        float2 st = make_float2(cp, sp);

        float2 a = make_float2(0.f, 0.f);
        int j = part * 20;
        #pragma unroll 4
        for (int i = 0; i < 20; ++i, ++j) {
            float2 xv = xb[j];
            a.x += xv.x * tv.x - xv.y * tv.y;
            a.y += xv.x * tv.y + xv.y * tv.x;
            float nx = tv.x * st.x - tv.y * st.y;
            tv.y = tv.x * st.y + tv.y * st.x;
            tv.x = nx;
        }
        a.x += __shfl_xor(a.x, 1); a.y += __shfl_xor(a.y, 1);
        a.x += __shfl_xor(a.x, 2); a.y += __shfl_xor(a.y, 2);
        if (part == 0) {
            if (o < FF) {
                Yt2[o + 20] = a;
                Yt2[(o < 60) ? (o + 100) : (o - 60)] = a;
            } else {
                Yp[o - FF] = a;
            }
        }
    }
    __syncthreads();

    // ---- Phase 2: build all 40 Z rows (3200 values, 5/thread), double-stored ----
    for (int i = 0; i < 5; ++i) {
        int zi = tid + i * NT;
        int jn = zi / FF;
        int g  = zi % FF;
        int n2 = jn - 20;
        int gm = g - n2; if (gm >= FF) gm -= FF; if (gm < 0) gm += FF;
        float2 a  = Yt2[g + 20], bm = Yt2[gm + 20];
        float2 cc = Yp[g],       dm = Yp[gm];
        float zre = a.x * bm.x + a.y * bm.y + cc.x * dm.x + cc.y * dm.y;
        float zim = a.y * bm.x - a.x * bm.y + cc.y * dm.x - cc.x * dm.y;
        float2 z = make_float2(zre, zim);
        Zall[jn][g + 20] = z;
        Zall[jn][(g < 60) ? (g + 100) : (g - 60)] = z;
    }
    __syncthreads();

    // ---- Phase 3: register sliding-window MAC over n1 ----
    float2 o0, o1, o2, o3, o4;
    int jn, fb;
    {
        jn = tid >> 4;          // n2 index 0..39
        int fg = tid & 15;
        fb = fg * 5;
        const float2* zz = Zall[jn];

        float2 S0 = make_float2(0.f,0.f), S1 = S0, S2 = S0, S3 = S0, S4 = S0;
        float2 w0 = zz[fb + 40], w1 = zz[fb + 41], w2 = zz[fb + 42],
               w3 = zz[fb + 43], w4 = zz[fb + 44];
        #pragma unroll
        for (int jn1 = 0; jn1 < 40; ++jn1) {
            float2 wv = Wsh[jn1 * 40 + jn];
            S0.x += wv.x * w0.x - wv.y * w0.y;  S0.y += wv.x * w0.y + wv.y * w0.x;
            S1.x += wv.x * w1.x - wv.y * w1.y;  S1.y += wv.x * w1.y + wv.y * w1.x;
            S2.x += wv.x * w2.x - wv.y * w2.y;  S2.y += wv.x * w2.y + wv.y * w2.x;
            S3.x += wv.x * w3.x - wv.y * w3.y;  S3.y += wv.x * w3.y + wv.y * w3.x;
            S4.x += wv.x * w4.x - wv.y * w4.y;  S4.y += wv.x * w4.y + wv.y * w4.x;
            if (jn1 < 39) {
                float2 nv = zz[fb + 39 - jn1];
                w4 = w3; w3 = w2; w2 = w1; w1 = w0; w0 = nv;
            }
        }
        float2 y;
        y = Yt2[fb + 0 - jn + 40]; o0 = make_float2(y.x*S0.x - y.y*S0.y, y.x*S0.y + y.y*S0.x);
        y = Yt2[fb + 1 - jn + 40]; o1 = make_float2(y.x*S1.x - y.y*S1.y, y.x*S1.y + y.y*S1.x);
        y = Yt2[fb + 2 - jn + 40]; o2 = make_float2(y.x*S2.x - y.y*S2.y, y.x*S2.y + y.y*S2.x);
        y = Yt2[fb + 3 - jn + 40]; o3 = make_float2(y.x*S3.x - y.y*S3.y, y.x*S3.y + y.y*S3.x);
        y = Yt2[fb + 4 - jn + 40]; o4 = make_float2(y.x*S4.x - y.y*S4.y, y.x*S4.y + y.y*S4.x);
    }
    __syncthreads();           // all Zall reads done before overlay writes
    flat[jn * FF + fb + 0] = o0;
    flat[jn * FF + fb + 1] = o1;
    flat[jn * FF + fb + 2] = o2;
    flat[jn * FF + fb + 3] = o3;
    flat[jn * FF + fb + 4] = o4;
    __syncthreads();

    // ---- tree-reduce 40 n2-partials: stage 1 (640 thr, 5 rows each) ----
    {
        int f = tid % FF;
        int p = tid / FF;      // 0..7
        float2 s = make_float2(0.f, 0.f);
        for (int q2 = 0; q2 < 5; ++q2) {
            float2 v = flat[(p * 5 + q2) * FF + f];
            s.x += v.x; s.y += v.y;
        }
        flat[3200 + p * FF + f] = s;
    }
    __syncthreads();
    if (tid < FF) {
        float2 s = make_float2(br[0], bi[0]);
        for (int p = 0; p < 8; ++p) {
            float2 v = flat[3200 + p * FF + tid];
            s.x += v.x; s.y += v.y;
        }
        dvec_g[((b * TT + t) * MCH + mi) * FF + tid] = s;   // unscaled spectrum
    }
}

// ---------------- Kernel 2: per-(sample,frame) iDFT + overlap + residual ----------------
// 2 threads per output sample (one per contributing frame), pair-combined by shuffle
__global__ void out_k2(
    const float* __restrict__ xr, const float* __restrict__ xi,
    const float* __restrict__ ti, const float2* __restrict__ dvec_g,
    float* __restrict__ out, int out_size)
{
    const int tot = BATCH * OUTL * MCH;   // 8160
    int idx2 = blockIdx.x * blockDim.x + threadIdx.x;
    bool active = idx2 < 2 * tot;

    float cx = 0.f, cy = 0.f, cov = 0.f;
    int p = 0, h = 0, b = 0, mi = 0, l = 0;
    if (active) {
        p  = idx2 >> 1;
        h  = idx2 & 1;
        mi = p % MCH;
        int rem = p / MCH;
        int lo  = rem % OUTL;
        b  = rem / OUTL;
        l  = lo + 20;
        int t1 = l / HOP;
        int tf = (h == 0) ? t1 : t1 - 1;
        if (tf >= 0 && tf <= TT - 1) {
            int j = l - HOP * tf;   // [0,40) for h=0, [40,80) for h=1
            const float2* dv = &dvec_g[((b * TT + tf) * MCH + mi) * FF];
            float ss, cc;
            sincosf((2.0f * PI_F / FF) * (float)j, &ss, &cc);
            float2 st = make_float2(cc, ss);      // e^{+i 2pi j/80}
            float2 tv = make_float2(1.f, 0.f);
            #pragma unroll 4
            for (int f = 0; f < FF; ++f) {
                float2 d = dv[f];
                cx += d.x * tv.x - d.y * tv.y;
                cy += d.x * tv.y + d.y * tv.x;
                float nx = tv.x * st.x - tv.y * st.y;
                tv.y = tv.x * st.y + tv.y * st.x;
                tv.x = nx;
            }
            cov = 1.f;
        }
    }
    // combine the two frame-contributions (lanes 2p, 2p+1)
    cx  += __shfl_xor(cx, 1);
    cy  += __shfl_xor(cy, 1);
    cov += __shfl_xor(cov, 1);

    if (active && h == 0) {
        float P   = exp2f(ti[b * 4] * 0.33219280948873623f) * 0.5f;  // 10^(x/10)/m
        float inv = 1.0f / ((float)FF * cov);
        float ar = cx * inv, ai = cy * inv;
        int gi = (b * LLEN + l) * MCH + mi;
        float outr = xr[gi] + ar * P;
        if (out_size == tot) {
            out[p] = outr;
        } else {
            out[p * 2]     = outr;
            out[p * 2 + 1] = xi[gi] + ai * P;
        }
    }
}

extern "C" void kernel_launch(void* const* d_in, const int* in_sizes, int n_in,
                              void* d_out, int out_size, void* d_ws, size_t ws_size,
                              hipStream_t stream)
{
    const float* xr = (const float*)d_in[0];
    const float* xi = (const float*)d_in[1];
    const float* ti = (const float*)d_in[2];
    const float* wr = (const float*)d_in[3];
    const float* wi = (const float*)d_in[4];
    const float* br = (const float*)d_in[5];
    const float* bi = (const float*)d_in[6];

    float2* dvec_g = (float2*)d_ws;   // 204*80 float2 = 130.6 KB

    fused_k1<<<NB, NT, 0, stream>>>(xr, xi, wr, wi, br, bi, dvec_g);

    int nthr = 2 * BATCH * OUTL * MCH;   // 16320
    out_k2<<<(nthr + 255) / 256, 256, 0, stream>>>(xr, xi, ti, dvec_g,
                                                   (float*)d_out, out_size);
}

// Round 6
// 18.952 us; speedup vs baseline: 3.7448x; 1.1290x over previous
//
#include <hip/hip_runtime.h>
#include <math.h>

#define BATCH 2
#define LLEN  2080
#define MCH   2
#define TT    51
#define FF    80
#define HOP   40
#define KW    1600
#define OUTL  2040
#define NT    640
#define NB    (BATCH * TT * MCH)   // 204
#define ZROW  161                  // padded row stride (float2) kills 4-way conflicts
#define PI_F  3.14159265358979323846f

// ---------------- Kernel 1: STFT + delta + iDFT, 204 blocks x 640 thr ----------------
__global__ __launch_bounds__(NT) void fused_k1(
    const float* __restrict__ xr, const float* __restrict__ xi,
    const float* __restrict__ wr, const float* __restrict__ wi,
    const float* __restrict__ br, const float* __restrict__ bi,
    float2* __restrict__ Fr)
{
    __shared__ float2 xs[2 * FF];     // frame t [0:80), frame t-1 [80:160)
    __shared__ float2 tw[FF];         // e^{+i 2pi r/80} (exact table)
    __shared__ float2 Yt2[2 * FF];    // double-stored Yt: Yt2[j] = Yt[(j-20)%80]
    __shared__ float2 Yp[FF];
    __shared__ float2 Wsh[KW];        // w, [n1][n2]
    __shared__ float2 Zall[40][ZROW]; // double-stored Z rows + 1 pad
    __shared__ float2 part[10][81];   // per-wave n2-partials (own LDS: no overlay barrier)
    __shared__ float2 dvec[FF];       // delta spectrum

    int tid  = threadIdx.x;
    int lane = tid & 63;
    int wave = tid >> 6;
    int bid = blockIdx.x;
    int b   = bid / (TT * MCH);
    int rem = bid % (TT * MCH);
    int t   = rem / MCH;
    int mi  = rem % MCH;
    int tp  = (t + TT - 1) % TT;

    // bias via uniform scalar load (off critical LDS path)
    float bre = br[0], bim = bi[0];

    // ---- Phase 0: x (160 thr), tw (80 thr), W (all threads) ----
    if (tid < 2 * FF) {
        int frm = tid / FF, j = tid % FF;
        int tt  = (frm == 0) ? t : tp;
        int g = (b * LLEN + tt * HOP + j) * MCH + mi;
        xs[tid] = make_float2(xr[g], xi[g]);
    } else if (tid < 240) {
        int jj = tid - 160;
        float s, c;
        sincosf((2.0f * PI_F / FF) * (float)jj, &s, &c);
        tw[jj] = make_float2(c, s);
    }
    for (int k = tid; k < KW; k += NT)
        Wsh[k] = make_float2(wr[k], wi[k]);
    __syncthreads();   // A

    // ---- Phase 1: STFT both frames; 160 outputs x 4 lane-adjacent partials ----
    {
        int o    = tid >> 2;       // 0..159
        int pq   = tid & 3;
        int ff   = o % FF;
        int frm  = o / FF;
        const float2* xb = &xs[frm * FF];
        float2 a = make_float2(0.f, 0.f);
        int j = pq * 20;
        int r = (ff * j) % FF;
        #pragma unroll 5
        for (int i = 0; i < 20; ++i, ++j) {
            float2 xv = xb[j];
            float2 tv = tw[r];              // use conj -> e^{-i 2pi ff j/80}
            a.x += xv.x * tv.x + xv.y * tv.y;
            a.y += xv.y * tv.x - xv.x * tv.y;
            r += ff; if (r >= FF) r -= FF;
        }
        a.x += __shfl_xor(a.x, 1); a.y += __shfl_xor(a.y, 1);
        a.x += __shfl_xor(a.x, 2); a.y += __shfl_xor(a.y, 2);
        if (pq == 0) {
            if (o < FF) {
                Yt2[o + 20] = a;
                Yt2[(o < 60) ? (o + 100) : (o - 60)] = a;
            } else {
                Yp[o - FF] = a;
            }
        }
    }
    __syncthreads();   // B

    // ---- Phase 2: build 40 Z rows (3200 values, 5/thread), double-stored ----
    for (int i = 0; i < 5; ++i) {
        int zi = tid + i * NT;
        int jn = zi / FF;
        int g  = zi % FF;
        int n2 = jn - 20;
        int gm = g - n2; if (gm >= FF) gm -= FF; if (gm < 0) gm += FF;
        float2 a  = Yt2[g + 20], bm = Yt2[gm + 20];
        float2 cc = Yp[g],       dm = Yp[gm];
        float zre = a.x * bm.x + a.y * bm.y + cc.x * dm.x + cc.y * dm.y;
        float zim = a.y * bm.x - a.x * bm.y + cc.y * dm.x - cc.x * dm.y;
        float2 z = make_float2(zre, zim);
        Zall[jn][g + 20] = z;
        Zall[jn][(g < 60) ? (g + 100) : (g - 60)] = z;
    }
    __syncthreads();   // C

    // ---- Phase 3: sliding-window MAC; in-wave reduce over 4 jn per wave ----
    {
        int jn = (wave << 2) | (lane >> 4);   // 0..39
        int fg = lane & 15;
        int fb = fg * 5;
        const float2* zz = &Zall[jn][0];

        float2 S0 = make_float2(0.f,0.f), S1 = S0, S2 = S0, S3 = S0, S4 = S0;
        float2 w0 = zz[fb + 40], w1 = zz[fb + 41], w2 = zz[fb + 42],
               w3 = zz[fb + 43], w4 = zz[fb + 44];
        #pragma unroll
        for (int jn1 = 0; jn1 < 40; ++jn1) {
            float2 wv = Wsh[jn1 * 40 + jn];
            S0.x += wv.x * w0.x - wv.y * w0.y;  S0.y += wv.x * w0.y + wv.y * w0.x;
            S1.x += wv.x * w1.x - wv.y * w1.y;  S1.y += wv.x * w1.y + wv.y * w1.x;
            S2.x += wv.x * w2.x - wv.y * w2.y;  S2.y += wv.x * w2.y + wv.y * w2.x;
            S3.x += wv.x * w3.x - wv.y * w3.y;  S3.y += wv.x * w3.y + wv.y * w3.x;
            S4.x += wv.x * w4.x - wv.y * w4.y;  S4.y += wv.x * w4.y + wv.y * w4.x;
            if (jn1 < 39) {
                float2 nv = zz[fb + 39 - jn1];
                w4 = w3; w3 = w2; w2 = w1; w1 = w0; w0 = nv;
            }
        }
        float2 y, o0, o1, o2, o3, o4;
        y = Yt2[fb + 0 - jn + 40]; o0 = make_float2(y.x*S0.x - y.y*S0.y, y.x*S0.y + y.y*S0.x);
        y = Yt2[fb + 1 - jn + 40]; o1 = make_float2(y.x*S1.x - y.y*S1.y, y.x*S1.y + y.y*S1.x);
        y = Yt2[fb + 2 - jn + 40]; o2 = make_float2(y.x*S2.x - y.y*S2.y, y.x*S2.y + y.y*S2.x);
        y = Yt2[fb + 3 - jn + 40]; o3 = make_float2(y.x*S3.x - y.y*S3.y, y.x*S3.y + y.y*S3.x);
        y = Yt2[fb + 4 - jn + 40]; o4 = make_float2(y.x*S4.x - y.y*S4.y, y.x*S4.y + y.y*S4.x);

        // reduce the wave's 4 jn values (lanes differ in bits 4,5)
        o0.x += __shfl_xor(o0.x,16); o0.y += __shfl_xor(o0.y,16);
        o0.x += __shfl_xor(o0.x,32); o0.y += __shfl_xor(o0.y,32);
        o1.x += __shfl_xor(o1.x,16); o1.y += __shfl_xor(o1.y,16);
        o1.x += __shfl_xor(o1.x,32); o1.y += __shfl_xor(o1.y,32);
        o2.x += __shfl_xor(o2.x,16); o2.y += __shfl_xor(o2.y,16);
        o2.x += __shfl_xor(o2.x,32); o2.y += __shfl_xor(o2.y,32);
        o3.x += __shfl_xor(o3.x,16); o3.y += __shfl_xor(o3.y,16);
        o3.x += __shfl_xor(o3.x,32); o3.y += __shfl_xor(o3.y,32);
        o4.x += __shfl_xor(o4.x,16); o4.y += __shfl_xor(o4.y,16);
        o4.x += __shfl_xor(o4.x,32); o4.y += __shfl_xor(o4.y,32);
        if ((lane >> 4) == 0) {
            part[wave][fb + 0] = o0;
            part[wave][fb + 1] = o1;
            part[wave][fb + 2] = o2;
            part[wave][fb + 3] = o3;
            part[wave][fb + 4] = o4;
        }
    }
    __syncthreads();   // E

    // ---- final n2-reduce: 80 threads sum 10 wave-partials + bias ----
    if (tid < FF) {
        float2 s = make_float2(bre, bim);
        #pragma unroll
        for (int r = 0; r < 10; ++r) {
            float2 v = part[r][tid];
            s.x += v.x; s.y += v.y;
        }
        dvec[tid] = s;
    }
    __syncthreads();   // F

    // ---- Phase 4: iDFT; 80 samples x 8 lane-adjacent partials x 10 MACs ----
    {
        int j  = tid >> 3;     // time sample 0..79
        int p8 = tid & 7;
        float2 a = make_float2(0.f, 0.f);
        int f0 = p8 * 10;
        int r  = (j * f0) % FF;
        #pragma unroll 5
        for (int i = 0; i < 10; ++i) {
            float2 dv = dvec[f0 + i];
            float2 tv = tw[r];             // e^{+i 2pi j f/80}
            a.x += dv.x * tv.x - dv.y * tv.y;
            a.y += dv.x * tv.y + dv.y * tv.x;
            r += j; if (r >= FF) r -= FF;
        }
        a.x += __shfl_xor(a.x, 1); a.y += __shfl_xor(a.y, 1);
        a.x += __shfl_xor(a.x, 2); a.y += __shfl_xor(a.y, 2);
        a.x += __shfl_xor(a.x, 4); a.y += __shfl_xor(a.y, 4);
        if (p8 == 0) {
            a.x *= (1.0f / FF);
            a.y *= (1.0f / FF);
            Fr[((b * TT + t) * MCH + mi) * FF + j] = a;
        }
    }
}

// ---------------- Kernel 2: overlap-add, cov, residual, slice ----------------
__global__ void out_kernel(
    const float* __restrict__ xr, const float* __restrict__ xi,
    const float* __restrict__ ti, const float2* __restrict__ Fr,
    float* __restrict__ out, int out_size)
{
    int idx = blockIdx.x * blockDim.x + threadIdx.x;
    int tot = BATCH * OUTL * MCH;
    if (idx >= tot) return;
    int mi  = idx % MCH;
    int rem = idx / MCH;
    int lo  = rem % OUTL;
    int b   = rem / OUTL;
    int l   = lo + 20;

    float P = exp2f(ti[b * 4] * 0.33219280948873623f) * 0.5f;  // 10^(x/10)/m

    int t1 = l / HOP;
    int t0 = t1 - 1;
    float2 acc = make_float2(0.f, 0.f);
    float cov = 0.f;
    if (t1 <= TT - 1) {
        float2 v = Fr[((b * TT + t1) * MCH + mi) * FF + (l - HOP * t1)];
        acc.x += v.x; acc.y += v.y; cov += 1.f;
    }
    if (t0 >= 0) {
        float2 v = Fr[((b * TT + t0) * MCH + mi) * FF + (l - HOP * t0)];
        acc.x += v.x; acc.y += v.y; cov += 1.f;
    }
    float inv = 1.0f / cov;
    acc.x *= inv; acc.y *= inv;

    int gi = (b * LLEN + l) * MCH + mi;
    float outr = xr[gi] + acc.x * P;
    if (out_size == tot) {
        out[idx] = outr;
    } else {
        float outi = xi[gi] + acc.y * P;
        out[idx * 2]     = outr;
        out[idx * 2 + 1] = outi;
    }
}

extern "C" void kernel_launch(void* const* d_in, const int* in_sizes, int n_in,
                              void* d_out, int out_size, void* d_ws, size_t ws_size,
                              hipStream_t stream)
{
    const float* xr = (const float*)d_in[0];
    const float* xi = (const float*)d_in[1];
    const float* ti = (const float*)d_in[2];
    const float* wr = (const float*)d_in[3];
    const float* wi = (const float*)d_in[4];
    const float* br = (const float*)d_in[5];
    const float* bi = (const float*)d_in[6];

    float2* Fr = (float2*)d_ws;   // 204*80 float2 = 130.6 KB

    fused_k1<<<NB, NT, 0, stream>>>(xr, xi, wr, wi, br, bi, Fr);

    int tot = BATCH * OUTL * MCH;   // 8160
    out_kernel<<<(tot + 255) / 256, 256, 0, stream>>>(xr, xi, ti, Fr,
                                                      (float*)d_out, out_size);
}

// Round 7
// 17.222 us; speedup vs baseline: 4.1209x; 1.1005x over previous
//
#include <hip/hip_runtime.h>
#include <math.h>

#define BATCH 2
#define LLEN  2080
#define MCH   2
#define TT    51
#define FF    80
#define HOP   40
#define KW    1600
#define OUTL  2040
#define NT    640
#define NB    (BATCH * TT * MCH)   // 204
#define ZROW  161                  // padded row stride (float2): 4-way -> 2-way bank aliasing
#define PI_F  3.14159265358979323846f

// ---------------- Kernel 1: STFT + delta + iDFT, 204 blocks x 640 thr ----------------
__global__ __launch_bounds__(NT) void fused_k1(
    const float* __restrict__ xr, const float* __restrict__ xi,
    const float* __restrict__ wr, const float* __restrict__ wi,
    const float* __restrict__ br, const float* __restrict__ bi,
    float2* __restrict__ Fr)
{
    __shared__ float2 xs[2 * FF];      // frame t [0:80), frame t-1 [80:160)
    __shared__ float2 tw[FF];          // e^{+i 2pi r/80} exact table (phase 4 only)
    __shared__ float2 Yt2[2 * FF];     // double-stored Yt: Yt2[j] = Yt[(j-20)%80]
    __shared__ float2 Yp[FF];
    __shared__ float2 Wsh[KW];         // w, [n1][n2] (written late, reg-staged)
    __shared__ float2 Zall[40][ZROW];  // padded Z rows; [0..3840) overlaid by reductions
    __shared__ float2 dvec[FF];

    float2* flat = &Zall[0][0];        // linear overlay scratch (40*161 = 6440 entries)

    int tid = threadIdx.x;
    int bid = blockIdx.x;
    int b   = bid / (TT * MCH);
    int rem = bid % (TT * MCH);
    int t   = rem / MCH;
    int mi  = rem % MCH;
    int tp  = (t + TT - 1) % TT;

    float bre = br[0], bim = bi[0];    // uniform scalar loads, hoisted

    // ---- Phase 0: issue w loads into registers (latency hides under phases 1-2) ----
    float2 wreg0 = make_float2(wr[tid],        wi[tid]);
    float2 wreg1 = make_float2(wr[tid + NT],   wi[tid + NT]);
    float2 wreg2 = make_float2(0.f, 0.f);
    if (tid < KW - 2 * NT)             // tid < 320
        wreg2 = make_float2(wr[tid + 2 * NT], wi[tid + 2 * NT]);

    // ---- Phase 0b: stage samples + exact twiddle table ----
    if (tid < 2 * FF) {
        int frm = tid / FF, j = tid % FF;
        int tt  = (frm == 0) ? t : tp;
        int g = (b * LLEN + tt * HOP + j) * MCH + mi;
        xs[tid] = make_float2(xr[g], xi[g]);
    } else if (tid < 240) {
        int jj = tid - 160;
        float s, c;
        sincosf((2.0f * PI_F / FF) * (float)jj, &s, &c);
        tw[jj] = make_float2(c, s);
    }
    __syncthreads();   // A

    // ---- Phase 1: STFT both frames; 160 outputs x 4 partials x 20 MACs ----
    // register twiddle: tv = e^{-i 2pi ff j/80}, exact quadrant seed at j0 = pq*20
    {
        int o    = tid >> 2;       // 0..159
        int pq   = tid & 3;
        int ff   = o % FF;
        int frm  = o / FF;
        const float2* xb = &xs[frm * FF];

        int q = (ff * pq) & 3;     // ff*j0 mod 80 = 20*q -> angle -(pi/2)*q
        float2 tv = (q == 0) ? make_float2(1.f, 0.f)
                  : (q == 1) ? make_float2(0.f, -1.f)
                  : (q == 2) ? make_float2(-1.f, 0.f)
                  :            make_float2(0.f, 1.f);
        float sp, cp;
        sincosf(-(2.0f * PI_F / FF) * (float)ff, &sp, &cp);
        float2 st = make_float2(cp, sp);   // e^{-i 2pi ff/80}

        float2 a = make_float2(0.f, 0.f);
        int j = pq * 20;
        #pragma unroll 4
        for (int i = 0; i < 20; ++i, ++j) {
            float2 xv = xb[j];
            a.x += xv.x * tv.x - xv.y * tv.y;
            a.y += xv.x * tv.y + xv.y * tv.x;
            float nx = tv.x * st.x - tv.y * st.y;
            tv.y = tv.x * st.y + tv.y * st.x;
            tv.x = nx;
        }
        flat[pq * 160 + o] = a;
    }
    __syncthreads();   // B
    if (tid < 2 * FF) {
        float2 s = make_float2(0.f, 0.f);
        for (int p = 0; p < 4; ++p) {
            float2 v = flat[p * 160 + tid];
            s.x += v.x; s.y += v.y;
        }
        if (tid < FF) {
            Yt2[tid + 20] = s;
            Yt2[(tid < 60) ? (tid + 100) : (tid - 60)] = s;
        } else {
            Yp[tid - FF] = s;
        }
    }
    __syncthreads();   // C

    // ---- Phase 2: build 40 Z rows (3200 values, 5/thread), double-stored ----
    for (int i = 0; i < 5; ++i) {
        int zi = tid + i * NT;
        int jn = zi / FF;
        int g  = zi % FF;
        int n2 = jn - 20;
        int gm = g - n2; if (gm >= FF) gm -= FF; if (gm < 0) gm += FF;
        float2 a  = Yt2[g + 20], bm = Yt2[gm + 20];
        float2 cc = Yp[g],       dm = Yp[gm];
        float zre = a.x * bm.x + a.y * bm.y + cc.x * dm.x + cc.y * dm.y;
        float zim = a.y * bm.x - a.x * bm.y + cc.y * dm.x - cc.x * dm.y;
        float2 z = make_float2(zre, zim);
        Zall[jn][g + 20] = z;
        Zall[jn][(g < 60) ? (g + 100) : (g - 60)] = z;
    }
    // write reg-staged w into LDS (loads long since landed)
    {
        Wsh[tid]      = wreg0;
        Wsh[tid + NT] = wreg1;
        if (tid < KW - 2 * NT) Wsh[tid + 2 * NT] = wreg2;
    }
    __syncthreads();   // D

    // ---- Phase 3: register sliding-window MAC over n1 ----
    float2 o0, o1, o2, o3, o4;
    int jn, fb;
    {
        jn = tid >> 4;          // n2 index 0..39
        int fg = tid & 15;
        fb = fg * 5;
        const float2* zz = &Zall[jn][0];

        float2 S0 = make_float2(0.f,0.f), S1 = S0, S2 = S0, S3 = S0, S4 = S0;
        float2 w0 = zz[fb + 40], w1 = zz[fb + 41], w2 = zz[fb + 42],
               w3 = zz[fb + 43], w4 = zz[fb + 44];
        #pragma unroll
        for (int jn1 = 0; jn1 < 40; ++jn1) {
            float2 wv = Wsh[jn1 * 40 + jn];
            S0.x += wv.x * w0.x - wv.y * w0.y;  S0.y += wv.x * w0.y + wv.y * w0.x;
            S1.x += wv.x * w1.x - wv.y * w1.y;  S1.y += wv.x * w1.y + wv.y * w1.x;
            S2.x += wv.x * w2.x - wv.y * w2.y;  S2.y += wv.x * w2.y + wv.y * w2.x;
            S3.x += wv.x * w3.x - wv.y * w3.y;  S3.y += wv.x * w3.y + wv.y * w3.x;
            S4.x += wv.x * w4.x - wv.y * w4.y;  S4.y += wv.x * w4.y + wv.y * w4.x;
            if (jn1 < 39) {
                float2 nv = zz[fb + 39 - jn1];
                w4 = w3; w3 = w2; w2 = w1; w1 = w0; w0 = nv;
            }
        }
        float2 y;
        y = Yt2[fb + 0 - jn + 40]; o0 = make_float2(y.x*S0.x - y.y*S0.y, y.x*S0.y + y.y*S0.x);
        y = Yt2[fb + 1 - jn + 40]; o1 = make_float2(y.x*S1.x - y.y*S1.y, y.x*S1.y + y.y*S1.x);
        y = Yt2[fb + 2 - jn + 40]; o2 = make_float2(y.x*S2.x - y.y*S2.y, y.x*S2.y + y.y*S2.x);
        y = Yt2[fb + 3 - jn + 40]; o3 = make_float2(y.x*S3.x - y.y*S3.y, y.x*S3.y + y.y*S3.x);
        y = Yt2[fb + 4 - jn + 40]; o4 = make_float2(y.x*S4.x - y.y*S4.y, y.x*S4.y + y.y*S4.x);
    }
    __syncthreads();   // E: all Zall reads done before overlay writes
    flat[jn * FF + fb + 0] = o0;
    flat[jn * FF + fb + 1] = o1;
    flat[jn * FF + fb + 2] = o2;
    flat[jn * FF + fb + 3] = o3;
    flat[jn * FF + fb + 4] = o4;
    __syncthreads();   // F

    // ---- tree-reduce 40 n2-partials: stage 1 (640 thr, 5 rows each) ----
    {
        int f = tid % FF;
        int p = tid / FF;      // 0..7
        float2 s = make_float2(0.f, 0.f);
        for (int q2 = 0; q2 < 5; ++q2) {
            float2 v = flat[(p * 5 + q2) * FF + f];
            s.x += v.x; s.y += v.y;
        }
        flat[3200 + p * FF + f] = s;
    }
    __syncthreads();   // G
    if (tid < FF) {
        float2 s = make_float2(bre, bim);
        #pragma unroll
        for (int p = 0; p < 8; ++p) {
            float2 v = flat[3200 + p * FF + tid];
            s.x += v.x; s.y += v.y;
        }
        dvec[tid] = s;
    }
    __syncthreads();   // H

    // ---- Phase 4: iDFT; 80 samples x 8 partials x 10 MACs (exact tw table) ----
    {
        int j  = tid >> 3;     // time sample 0..79
        int p8 = tid & 7;
        float2 a = make_float2(0.f, 0.f);
        int f0 = p8 * 10;
        int r  = (j * f0) % FF;
        #pragma unroll 5
        for (int i = 0; i < 10; ++i) {
            float2 dv = dvec[f0 + i];
            float2 tv = tw[r];             // e^{+i 2pi j f/80}
            a.x += dv.x * tv.x - dv.y * tv.y;
            a.y += dv.x * tv.y + dv.y * tv.x;
            r += j; if (r >= FF) r -= FF;
        }
        flat[p8 * FF + j] = a;
    }
    __syncthreads();   // I
    if (tid < FF) {
        float2 s = make_float2(0.f, 0.f);
        #pragma unroll
        for (int p = 0; p < 8; ++p) {
            float2 v = flat[p * FF + tid];
            s.x += v.x; s.y += v.y;
        }
        s.x *= (1.0f / FF);
        s.y *= (1.0f / FF);
        Fr[((b * TT + t) * MCH + mi) * FF + tid] = s;
    }
}

// ---------------- Kernel 2: overlap-add, cov, residual, slice ----------------
__global__ void out_kernel(
    const float* __restrict__ xr, const float* __restrict__ xi,
    const float* __restrict__ ti, const float2* __restrict__ Fr,
    float* __restrict__ out, int out_size)
{
    int idx = blockIdx.x * blockDim.x + threadIdx.x;
    int tot = BATCH * OUTL * MCH;
    if (idx >= tot) return;
    int mi  = idx % MCH;
    int rem = idx / MCH;
    int lo  = rem % OUTL;
    int b   = rem / OUTL;
    int l   = lo + 20;

    float P = exp2f(ti[b * 4] * 0.33219280948873623f) * 0.5f;  // 10^(x/10)/m

    int t1 = l / HOP;
    int t0 = t1 - 1;
    float2 acc = make_float2(0.f, 0.f);
    float cov = 0.f;
    if (t1 <= TT - 1) {
        float2 v = Fr[((b * TT + t1) * MCH + mi) * FF + (l - HOP * t1)];
        acc.x += v.x; acc.y += v.y; cov += 1.f;
    }
    if (t0 >= 0) {
        float2 v = Fr[((b * TT + t0) * MCH + mi) * FF + (l - HOP * t0)];
        acc.x += v.x; acc.y += v.y; cov += 1.f;
    }
    float inv = 1.0f / cov;
    acc.x *= inv; acc.y *= inv;

    int gi = (b * LLEN + l) * MCH + mi;
    float outr = xr[gi] + acc.x * P;
    if (out_size == tot) {
        out[idx] = outr;
    } else {
        float outi = xi[gi] + acc.y * P;
        out[idx * 2]     = outr;
        out[idx * 2 + 1] = outi;
    }
}

extern "C" void kernel_launch(void* const* d_in, const int* in_sizes, int n_in,
                              void* d_out, int out_size, void* d_ws, size_t ws_size,
                              hipStream_t stream)
{
    const float* xr = (const float*)d_in[0];
    const float* xi = (const float*)d_in[1];
    const float* ti = (const float*)d_in[2];
    const float* wr = (const float*)d_in[3];
    const float* wi = (const float*)d_in[4];
    const float* br = (const float*)d_in[5];
    const float* bi = (const float*)d_in[6];

    float2* Fr = (float2*)d_ws;   // 204*80 float2 = 130.6 KB

    fused_k1<<<NB, NT, 0, stream>>>(xr, xi, wr, wi, br, bi, Fr);

    int tot = BATCH * OUTL * MCH;   // 8160
    out_kernel<<<(tot + 255) / 256, 256, 0, stream>>>(xr, xi, ti, Fr,
                                                      (float*)d_out, out_size);
}